// Round 2
// baseline (517.655 us; speedup 1.0000x reference)
//
#include <hip/hip_runtime.h>

// Problem constants: B=8, N_IN=256, N=8192, D=64, K=512
#define B_SZ   8
#define NIN    256
#define NCOL   8192
#define DDIM   64
#define KCODES 512
#define ZQ_ELEMS (8ull * 64ull * 8192ull)   // zq floats; hist follows

// ---------------------------------------------------------------------------
// Prep: Wt[i][d] = W[d][i] (so conv's wave-uniform reads are contiguous ->
// s_load_dwordx16); emb_sq[k] = ||emb[k]||^2; hist_out = ind_hist (re-init
// every call, harness does not re-poison).
// ---------------------------------------------------------------------------
__global__ __launch_bounds__(256) void vq_prep(const float* __restrict__ W,
                                               const float* __restrict__ emb,
                                               const float* __restrict__ ind_hist,
                                               float* __restrict__ Wt,
                                               float* __restrict__ emb_sq,
                                               float* __restrict__ hist_out)
{
    int t = blockIdx.x * 256 + threadIdx.x;
    if (t < NIN * DDIM) {
        int i = t >> 6;      // row of Wt  (0..255)
        int d = t & 63;      // col of Wt  (0..63)
        Wt[t] = W[d * NIN + i];
    }
    if (t < KCODES) {
        const float* __restrict__ ek = emb + t * DDIM;
        float s = 0.f;
        #pragma unroll
        for (int d = 0; d < DDIM; ++d) s = fmaf(ek[d], ek[d], s);
        emb_sq[t] = s;
        hist_out[t] = ind_hist[t];
    }
}

// ---------------------------------------------------------------------------
// Main kernel: block owns 64 columns. Two phases:
//   conv:   wave w computes d-slice [16w,16w+16) for all 64 cols.
//           z loads coalesced (lane=col); Wt via scalar s_load (readfirstlane).
//           Same sequential-i fmaf order as the verified round-1 kernel.
//   search: quad of lanes owns one column; lane q holds d-slice [16q,16q+16).
//           Per k: 16 FMA + quad shfl_xor reduce; first-min tie-break.
// Hist: one atomicAdd per column (lane q==0). Output: straight-through zq.
// ---------------------------------------------------------------------------
__global__ __launch_bounds__(256, 4) void vq_main(const float* __restrict__ z,
                                                  const float* __restrict__ Wt,
                                                  const float* __restrict__ emb,
                                                  const float* __restrict__ emb_sq,
                                                  float* __restrict__ out,
                                                  float* __restrict__ hist)
{
    __shared__ float ze_lds[64][DDIM + 4];   // stride 68 floats: pad for banks

    const int tid = threadIdx.x;

    // ---------------- conv phase ----------------
    {
        const int cl = tid & 63;                                   // column
        const int qc = __builtin_amdgcn_readfirstlane(tid >> 6);   // wave slice
        const int C  = blockIdx.x * 64 + cl;
        const int b  = C >> 13;
        const int n  = C & (NCOL - 1);
        const float* __restrict__ zp = z + (size_t)b * NIN * NCOL + n;
        const float* __restrict__ wp = Wt + qc * 16;

        float acc[16];
        #pragma unroll
        for (int j = 0; j < 16; ++j) acc[j] = 0.f;

        for (int i = 0; i < NIN; i += 2) {
            float z0 = zp[(size_t)(i + 0) * NCOL];
            float z1 = zp[(size_t)(i + 1) * NCOL];
            const float* __restrict__ w0 = wp + (size_t)i * DDIM;  // s_load
            const float* __restrict__ w1 = w0 + DDIM;
            #pragma unroll
            for (int j = 0; j < 16; ++j) {
                float a = acc[j];
                a = fmaf(w0[j], z0, a);   // i ascending: ze bit-matches round 1
                a = fmaf(w1[j], z1, a);
                acc[j] = a;
            }
        }
        #pragma unroll
        for (int j = 0; j < 16; ++j) ze_lds[cl][qc * 16 + j] = acc[j];
    }
    __syncthreads();

    // ---------------- search phase ----------------
    const int q  = tid & 3;        // d-slice within quad
    const int cl = tid >> 2;       // column within block
    const int C  = blockIdx.x * 64 + cl;
    const int b  = C >> 13;
    const int n  = C & (NCOL - 1);

    float ze_r[16];
    #pragma unroll
    for (int j = 0; j < 16; ++j) ze_r[j] = ze_lds[cl][q * 16 + j];

    float zesq = 0.f;
    #pragma unroll
    for (int j = 0; j < 16; ++j) zesq = fmaf(ze_r[j], ze_r[j], zesq);
    zesq += __shfl_xor(zesq, 1);
    zesq += __shfl_xor(zesq, 2);

    float best = 3.4e38f;
    int bestk = 0;
    const float4* __restrict__ e4base =
        reinterpret_cast<const float4*>(emb) + q * 4;   // q*16 floats

    #pragma unroll 2
    for (int k = 0; k < KCODES; ++k) {
        const float4* __restrict__ e4 = e4base + (size_t)k * 16;  // row = 16 f4
        float4 ea = e4[0];
        float4 eb = e4[1];
        float4 ec = e4[2];
        float4 ed = e4[3];
        float cr = 0.f;
        cr = fmaf(ea.x, ze_r[ 0], cr); cr = fmaf(ea.y, ze_r[ 1], cr);
        cr = fmaf(ea.z, ze_r[ 2], cr); cr = fmaf(ea.w, ze_r[ 3], cr);
        cr = fmaf(eb.x, ze_r[ 4], cr); cr = fmaf(eb.y, ze_r[ 5], cr);
        cr = fmaf(eb.z, ze_r[ 6], cr); cr = fmaf(eb.w, ze_r[ 7], cr);
        cr = fmaf(ec.x, ze_r[ 8], cr); cr = fmaf(ec.y, ze_r[ 9], cr);
        cr = fmaf(ec.z, ze_r[10], cr); cr = fmaf(ec.w, ze_r[11], cr);
        cr = fmaf(ed.x, ze_r[12], cr); cr = fmaf(ed.y, ze_r[13], cr);
        cr = fmaf(ed.z, ze_r[14], cr); cr = fmaf(ed.w, ze_r[15], cr);
        cr += __shfl_xor(cr, 1);       // quad tree-reduce (DPP)
        cr += __shfl_xor(cr, 2);
        float dist = (zesq + emb_sq[k]) - 2.0f * cr;   // ref formula order
        if (dist < best) { best = dist; bestk = k; }   // first-min tie-break
    }

    // ---- histogram: quad lanes agree on bestk; one atomic per column ----
    if (q == 0) atomicAdd(hist + bestk, 1.0f);

    // ---- straight-through output: ze + (zq - ze) ----
    const float4* __restrict__ ebest =
        reinterpret_cast<const float4*>(emb + (size_t)bestk * DDIM) + q * 4;
    float* __restrict__ op = out + ((size_t)b * DDIM + q * 16) * NCOL + n;
    #pragma unroll
    for (int v = 0; v < 4; ++v) {
        float4 e = ebest[v];
        op[(size_t)(4 * v + 0) * NCOL] = ze_r[4 * v + 0] + (e.x - ze_r[4 * v + 0]);
        op[(size_t)(4 * v + 1) * NCOL] = ze_r[4 * v + 1] + (e.y - ze_r[4 * v + 1]);
        op[(size_t)(4 * v + 2) * NCOL] = ze_r[4 * v + 2] + (e.z - ze_r[4 * v + 2]);
        op[(size_t)(4 * v + 3) * NCOL] = ze_r[4 * v + 3] + (e.w - ze_r[4 * v + 3]);
    }
}

// ---------------------------------------------------------------------------
extern "C" void kernel_launch(void* const* d_in, const int* in_sizes, int n_in,
                              void* d_out, int out_size, void* d_ws, size_t ws_size,
                              hipStream_t stream)
{
    const float* z        = (const float*)d_in[0];  // (8, 256, 8192)
    const float* W        = (const float*)d_in[1];  // (64, 256)
    const float* emb      = (const float*)d_in[2];  // (512, 64)
    const float* ind_hist = (const float*)d_in[3];  // (512,)

    float* out  = (float*)d_out;                    // zq then hist
    float* hist = out + ZQ_ELEMS;

    float* Wt     = (float*)d_ws;                   // NIN*DDIM floats
    float* emb_sq = Wt + NIN * DDIM;                // KCODES floats

    hipLaunchKernelGGL(vq_prep, dim3(64), dim3(256), 0, stream,
                       W, emb, ind_hist, Wt, emb_sq, hist);

    // 65536 columns, 4 threads each -> 1024 blocks of 256
    hipLaunchKernelGGL(vq_main, dim3(1024), dim3(256), 0, stream,
                       z, Wt, emb, emb_sq, out, hist);
}

// Round 3
// 134.214 us; speedup vs baseline: 3.8569x; 3.8569x over previous
//
#include <hip/hip_runtime.h>

// Problem constants: B=8, N_IN=256, N=8192, D=64, K=512
#define B_SZ   8
#define NIN    256
#define NCOL   8192
#define DDIM   64
#define KCODES 512
#define ZQ_ELEMS (8ull * 64ull * 8192ull)   // zq floats; hist follows

// ---------------------------------------------------------------------------
// Prep: Wt[i][d] = W[d][i] (conv's wave-uniform reads contiguous -> s_load);
// emb_sq[k] = ||emb[k]||^2; hist_out = ind_hist (re-init every call).
// ---------------------------------------------------------------------------
__global__ __launch_bounds__(256) void vq_prep(const float* __restrict__ W,
                                               const float* __restrict__ emb,
                                               const float* __restrict__ ind_hist,
                                               float* __restrict__ Wt,
                                               float* __restrict__ emb_sq,
                                               float* __restrict__ hist_out)
{
    int t = blockIdx.x * 256 + threadIdx.x;
    if (t < NIN * DDIM) {
        int i = t >> 6;
        int d = t & 63;
        Wt[t] = W[d * NIN + i];
    }
    if (t < KCODES) {
        const float* __restrict__ ek = emb + t * DDIM;
        float s = 0.f;
        #pragma unroll
        for (int d = 0; d < DDIM; ++d) s = fmaf(ek[d], ek[d], s);
        emb_sq[t] = s;
        hist_out[t] = ind_hist[t];
    }
}

// ---------------------------------------------------------------------------
// Main: block (256 thr / 4 waves) owns 64 columns.
//  conv   : wave w computes d-slice [16w,16w+16) for all 64 cols (lane=col,
//           Wt via s_load, ascending-i fmaf — bit-identical to round 1/2 ze).
//  search : every thread holds its column's FULL ze[64] in VGPRs; wave w
//           scans k in [128w, 128w+128). emb[k] is wave-uniform -> s_load;
//           64-FMA ascending-d chain (round-1 dist order). No per-lane
//           vector loads in the hot loop.
//  combine: 4 per-wave (best,bestk) candidates merged via LDS, strict-<
//           ascending-w scan = jnp.argmin first-min tie-break.
//  epilog : wave w stores zq d-slice [16w,16w+16); hist atomic from wave 0.
// ---------------------------------------------------------------------------
__global__ __launch_bounds__(256, 4) void vq_main(const float* __restrict__ z,
                                                  const float* __restrict__ Wt,
                                                  const float* __restrict__ emb,
                                                  const float* __restrict__ emb_sq,
                                                  float* __restrict__ out,
                                                  float* __restrict__ hist)
{
    __shared__ float ze_lds[64][DDIM + 4];   // stride 68 floats
    __shared__ float bw_lds[4][64];
    __shared__ int   bk_lds[4][64];

    const int tid = threadIdx.x;
    const int cl  = tid & 63;                                   // column (lane)
    const int w   = __builtin_amdgcn_readfirstlane(tid >> 6);   // wave id 0..3
    const int C   = blockIdx.x * 64 + cl;
    const int b   = C >> 13;
    const int n   = C & (NCOL - 1);

    // ---------------- conv phase (verified round-2 code) ----------------
    {
        const float* __restrict__ zp = z + (size_t)b * NIN * NCOL + n;
        const float* __restrict__ wp = Wt + w * 16;

        float acc[16];
        #pragma unroll
        for (int j = 0; j < 16; ++j) acc[j] = 0.f;

        for (int i = 0; i < NIN; i += 2) {
            float z0 = zp[(size_t)(i + 0) * NCOL];
            float z1 = zp[(size_t)(i + 1) * NCOL];
            const float* __restrict__ w0 = wp + (size_t)i * DDIM;  // s_load
            const float* __restrict__ w1 = w0 + DDIM;
            #pragma unroll
            for (int j = 0; j < 16; ++j) {
                float a = acc[j];
                a = fmaf(w0[j], z0, a);
                a = fmaf(w1[j], z1, a);
                acc[j] = a;
            }
        }
        #pragma unroll
        for (int j = 0; j < 16; ++j) ze_lds[cl][w * 16 + j] = acc[j];
    }
    __syncthreads();

    // ---------------- pull full column into VGPRs ----------------
    float ze[DDIM];
    #pragma unroll
    for (int j = 0; j < DDIM / 4; ++j) {
        float4 v = *reinterpret_cast<const float4*>(&ze_lds[cl][4 * j]);
        ze[4 * j + 0] = v.x;
        ze[4 * j + 1] = v.y;
        ze[4 * j + 2] = v.z;
        ze[4 * j + 3] = v.w;
    }

    float zesq = 0.f;
    #pragma unroll
    for (int d = 0; d < DDIM; ++d) zesq = fmaf(ze[d], ze[d], zesq);

    // ---------------- search phase: wave w owns k in [128w, 128w+128) ----
    float best = 3.4e38f;
    int bestk = KCODES * w / 4;
    const int k0 = w * (KCODES / 4);
    for (int kk = 0; kk < KCODES / 4; ++kk) {
        const int k = k0 + kk;
        const float* __restrict__ ek = emb + (size_t)k * DDIM;  // s_load
        float cr = 0.f;
        #pragma unroll
        for (int d = 0; d < DDIM; ++d) cr = fmaf(ek[d], ze[d], cr);
        float dist = (zesq + emb_sq[k]) - 2.0f * cr;   // round-1 order
        if (dist < best) { best = dist; bestk = k; }   // first-min tie-break
    }
    bw_lds[w][cl] = best;
    bk_lds[w][cl] = bestk;
    __syncthreads();

    // ---------------- combine 4 candidates (ascending w, strict <) -------
    float fb = bw_lds[0][cl];
    int   fk = bk_lds[0][cl];
    #pragma unroll
    for (int ww = 1; ww < 4; ++ww) {
        float v = bw_lds[ww][cl];
        int   kv = bk_lds[ww][cl];
        if (v < fb) { fb = v; fk = kv; }
    }

    // ---------------- histogram: one atomic per column -------------------
    if (w == 0) atomicAdd(hist + fk, 1.0f);

    // ---------------- straight-through output: wave w writes its d-slice -
    const float4* __restrict__ eb =
        reinterpret_cast<const float4*>(emb + (size_t)fk * DDIM) + w * 4;
    float* __restrict__ op = out + ((size_t)b * DDIM + w * 16) * NCOL + n;
    #pragma unroll
    for (int v = 0; v < 4; ++v) {
        float4 e = eb[v];
        float z0 = ze_lds[cl][w * 16 + 4 * v + 0];   // LDS: no runtime reg idx
        float z1 = ze_lds[cl][w * 16 + 4 * v + 1];
        float z2 = ze_lds[cl][w * 16 + 4 * v + 2];
        float z3 = ze_lds[cl][w * 16 + 4 * v + 3];
        op[(size_t)(4 * v + 0) * NCOL] = z0 + (e.x - z0);
        op[(size_t)(4 * v + 1) * NCOL] = z1 + (e.y - z1);
        op[(size_t)(4 * v + 2) * NCOL] = z2 + (e.z - z2);
        op[(size_t)(4 * v + 3) * NCOL] = z3 + (e.w - z3);
    }
}

// ---------------------------------------------------------------------------
extern "C" void kernel_launch(void* const* d_in, const int* in_sizes, int n_in,
                              void* d_out, int out_size, void* d_ws, size_t ws_size,
                              hipStream_t stream)
{
    const float* z        = (const float*)d_in[0];  // (8, 256, 8192)
    const float* W        = (const float*)d_in[1];  // (64, 256)
    const float* emb      = (const float*)d_in[2];  // (512, 64)
    const float* ind_hist = (const float*)d_in[3];  // (512,)

    float* out  = (float*)d_out;                    // zq then hist
    float* hist = out + ZQ_ELEMS;

    float* Wt     = (float*)d_ws;                   // NIN*DDIM floats
    float* emb_sq = Wt + NIN * DDIM;                // KCODES floats

    hipLaunchKernelGGL(vq_prep, dim3(64), dim3(256), 0, stream,
                       W, emb, ind_hist, Wt, emb_sq, hist);

    // 64 columns per block -> 1024 blocks of 256 (4 blocks/CU, 16 waves/CU)
    hipLaunchKernelGGL(vq_main, dim3(1024), dim3(256), 0, stream,
                       z, Wt, emb, emb_sq, out, hist);
}